// Round 4
// baseline (225.101 us; speedup 1.0000x reference)
//
#include <hip/hip_runtime.h>
#include <hip/hip_bf16.h>

#define NPTS 12288
#define DD 128
#define CHUNKS 16
#define CHW (NPTS / CHUNKS)   // 768 cols per chunk
#define TILES (CHW / 64)      // 12 col-tiles of 64
#define NBANDS (NPTS / 64)    // 192 row bands

// descriptors pre-scaled by sqrt(10 * log2(e)) so MFMA result a = S*log2(e);
// then e^S = exp2(a) directly and argmax keys come from bits(exp2(a)).
#define PRESCALE 3.79828262f

typedef short bf16x8 __attribute__((ext_vector_type(8)));
typedef float f32x4 __attribute__((ext_vector_type(4)));

__device__ __forceinline__ float fast_exp2(float x) {
#if defined(__has_builtin)
#if __has_builtin(__builtin_amdgcn_exp2f)
  return __builtin_amdgcn_exp2f(x);
#else
  return exp2f(x);
#endif
#else
  return exp2f(x);
#endif
}

__device__ __forceinline__ short f2bf(float f) {  // RNE f32 -> bf16
  unsigned u = __float_as_uint(f);
  u += 0x7FFFu + ((u >> 16) & 1u);
  return (short)(u >> 16);
}

__device__ __forceinline__ unsigned umax(unsigned a, unsigned b) { return a > b ? a : b; }

// ---------------- pure conversion: f32 -> prescaled bf16 ----------------
__global__ void k_conv(const float* __restrict__ d0, const float* __restrict__ d1,
                       short* __restrict__ o0, short* __restrict__ o1) {
  unsigned t = blockIdx.x * 256u + threadIdx.x;
  const unsigned half = (NPTS * DD) / 4;
  const float* src; short* dst; unsigned g;
  if (t < half) { src = d0; dst = o0; g = t; }
  else          { src = d1; dst = o1; g = t - half; }
  float4 v = *(const float4*)(src + (size_t)g * 4);
  short4 r;
  r.x = f2bf(v.x * PRESCALE); r.y = f2bf(v.y * PRESCALE);
  r.z = f2bf(v.z * PRESCALE); r.w = f2bf(v.w * PRESCALE);
  *(short4*)(dst + (size_t)g * 4) = r;
}

// ---------------- main fused kernel ----------------
// block = (band, chunk-group of 4). A band (64x128 bf16 = 16KB) staged once in
// LDS with XOR swizzle (G4: row-major D=128 is a 16-way conflict otherwise),
// shared by 4 waves; each wave owns one chunk (768 cols, 12 tiles of 64).
// Per kk: 4 ds_read_b128 (A frags) + 4 global bf16x8 (B frags) + 16 MFMA.
// C-frag: col = lane&15, row = (lane>>4)*4 + reg (m89/m91, verified R1-R3).
// launch_bounds(256,3): est live set ~156 regs < 170 budget -> 3 waves/SIMD.
__launch_bounds__(256, 3)
__global__ void k_main(const short* __restrict__ d0b, const short* __restrict__ d1b,
                       uint2* __restrict__ colKV, uint2* __restrict__ rowKV) {
  __shared__ __align__(16) char aLds[64 * 256];   // 16 KB
  const int widx = threadIdx.x >> 6;
  const int lane = threadIdx.x & 63;
  const int lo = lane & 15, hi = lane >> 4;
  const int band = blockIdx.x >> 2;                // 0..191
  const int cg = blockIdx.x & 3;
  const int chunk = cg * 4 + widx;                 // 0..15
  const int row0 = band * 64;
  const int cbase = chunk * CHW;

  // stage A band into LDS, swizzled: lds[byte ^ ((row&7)<<4)] = global[byte]
  {
    const char* src = (const char*)(d0b + (size_t)row0 * DD);
    #pragma unroll
    for (int it = 0; it < 4; it++) {
      int byte = (it * 256 + threadIdx.x) * 16;    // 0..16383
      int row = byte >> 8;
      int swz = byte ^ ((row & 7) << 4);
      *(int4*)(aLds + swz) = *(const int4*)(src + byte);
    }
  }
  __syncthreads();

  float rowsum[4][4];
  unsigned rowkey[4][4], rowcomp[4][4];
  #pragma unroll
  for (int i = 0; i < 4; i++)
    #pragma unroll
    for (int r = 0; r < 4; r++) {
      rowsum[i][r] = 0.f;
      rowkey[i][r] = 0u;
      rowcomp[i][r] = 0x3FFFu - (unsigned)(row0 + i * 16 + hi * 4 + r);
    }

  const short* bp0 = d1b + (size_t)cbase * DD;
  const int axor = (lo & 7) << 4;                  // lane-constant LDS swizzle term

  for (int t = 0; t < TILES; t++) {
    // opaque zero: keeps the 16 A ds_reads inside the t-loop (prevents LICM
    // re-hoisting them into 64 persistent VGPRs)
    int tblur = 0;
    asm volatile("" : "+v"(tblur));

    f32x4 acc[4][4];
    #pragma unroll
    for (int i = 0; i < 4; i++)
      #pragma unroll
      for (int j = 0; j < 4; j++)
        acc[i][j] = (f32x4){0.f, 0.f, 0.f, 0.f};

    const short* bpt = bp0 + (size_t)t * 64 * DD;

    #pragma unroll
    for (int kk = 0; kk < 4; kk++) {
      bf16x8 bfr[4];
      #pragma unroll
      for (int j = 0; j < 4; j++)
        bfr[j] = *(const bf16x8*)(bpt + (size_t)(j * 16 + lo) * DD + kk * 32 + hi * 8);
      bf16x8 afr[4];
      #pragma unroll
      for (int i = 0; i < 4; i++) {
        int abyte = (((i << 4) + lo) << 8) + (kk << 6) + (hi << 4);
        abyte ^= axor;
        afr[i] = *(const bf16x8*)(aLds + abyte + tblur);
      }
      #pragma unroll
      for (int j = 0; j < 4; j++)
        #pragma unroll
        for (int i = 0; i < 4; i++)
          acc[i][j] = __builtin_amdgcn_mfma_f32_16x16x32_bf16(afr[i], bfr[j], acc[i][j], 0, 0, 0);
    }

    // fused epilogue: e = e^S = exp2(a); keys from bits(e) (monotone), both directions
    const int ct = cbase + t * 64;
    #pragma unroll
    for (int j = 0; j < 4; j++) {
      float colsum = 0.f;
      unsigned colkey = 0u;
      const unsigned ccomp = 0x3FFFu - (unsigned)(ct + j * 16 + lo);
      #pragma unroll
      for (int i = 0; i < 4; i++)
        #pragma unroll
        for (int r = 0; r < 4; r++) {
          float e = fast_exp2(acc[i][j][r]);
          unsigned tb = __float_as_uint(e) & 0xFFFFC000u;
          rowkey[i][r] = umax(rowkey[i][r], tb | ccomp);
          colkey = umax(colkey, tb | rowcomp[i][r]);
          rowsum[i][r] += e;
          colsum += e;
        }
      colsum += __shfl_xor(colsum, 16, 64);
      colsum += __shfl_xor(colsum, 32, 64);
      colkey = umax(colkey, (unsigned)__shfl_xor((int)colkey, 16, 64));
      colkey = umax(colkey, (unsigned)__shfl_xor((int)colkey, 32, 64));
      if (hi == 0) {
        int c = ct + j * 16 + lo;
        colKV[(size_t)band * NPTS + c] = make_uint2(colkey, __float_as_uint(colsum));
      }
    }
  }

  // row partials: reduce over lo bits (cols), lanes with lo==0 write
  #pragma unroll
  for (int i = 0; i < 4; i++)
    #pragma unroll
    for (int r = 0; r < 4; r++) {
      float s = rowsum[i][r];
      unsigned k = rowkey[i][r];
      s += __shfl_xor(s, 1, 64); s += __shfl_xor(s, 2, 64);
      s += __shfl_xor(s, 4, 64); s += __shfl_xor(s, 8, 64);
      k = umax(k, (unsigned)__shfl_xor((int)k, 1, 64));
      k = umax(k, (unsigned)__shfl_xor((int)k, 2, 64));
      k = umax(k, (unsigned)__shfl_xor((int)k, 4, 64));
      k = umax(k, (unsigned)__shfl_xor((int)k, 8, 64));
      if (lo == 0) {
        int row = row0 + i * 16 + hi * 4 + r;
        rowKV[(size_t)chunk * NPTS + row] = make_uint2(k, __float_as_uint(s));
      }
    }
}

// ---------------- fused reduce (+ exact positive dots): blocks 0..47 cols, 48..95 rows ----
__global__ void k_red(const uint2* __restrict__ colKV, const uint2* __restrict__ rowKV,
                      const float* __restrict__ d0, const float* __restrict__ d1,
                      const int* __restrict__ c0, const int* __restrict__ c1,
                      unsigned* __restrict__ best0, unsigned* __restrict__ best1,
                      float* __restrict__ l0part, float* __restrict__ l1part) {
  float v;
  if (blockIdx.x < 48) {
    int m = blockIdx.x * 256 + threadIdx.x;
    float s = 0.f; unsigned k = 0u;
    #pragma unroll 8
    for (int b = 0; b < NBANDS; b++) {
      uint2 kv = colKV[(size_t)b * NPTS + m];
      s += __uint_as_float(kv.y);
      k = umax(k, kv.x);
    }
    best1[m] = 0x3FFFu - (k & 0x3FFFu);
    int cc = c1[m];
    int i = cc > 0 ? cc : 0;
    const float4* pa = (const float4*)(d0 + (size_t)i * DD);
    const float4* pb = (const float4*)(d1 + (size_t)m * DD);
    float dot = 0.f;
    #pragma unroll 8
    for (int q = 0; q < DD / 4; q++) {
      float4 a = pa[q], b = pb[q];
      dot += a.x * b.x + a.y * b.y + a.z * b.z + a.w * b.w;
    }
    v = (cc >= 0) ? (logf(s) - 10.0f * dot) : 0.f;
  } else {
    int n = (blockIdx.x - 48) * 256 + threadIdx.x;
    float s = 0.f; unsigned k = 0u;
    #pragma unroll
    for (int c = 0; c < CHUNKS; c++) {
      uint2 kv = rowKV[(size_t)c * NPTS + n];
      s += __uint_as_float(kv.y);
      k = umax(k, kv.x);
    }
    best0[n] = 0x3FFFu - (k & 0x3FFFu);
    int cc = c0[n];
    int i = cc > 0 ? cc : 0;
    const float4* pa = (const float4*)(d0 + (size_t)n * DD);
    const float4* pb = (const float4*)(d1 + (size_t)i * DD);
    float dot = 0.f;
    #pragma unroll 8
    for (int q = 0; q < DD / 4; q++) {
      float4 a = pa[q], b = pb[q];
      dot += a.x * b.x + a.y * b.y + a.z * b.z + a.w * b.w;
    }
    v = (cc >= 0) ? (logf(s) - 10.0f * dot) : 0.f;
  }
  __shared__ float red[256];
  red[threadIdx.x] = v; __syncthreads();
  for (int st = 128; st > 0; st >>= 1) {
    if (threadIdx.x < st) red[threadIdx.x] += red[threadIdx.x + st];
    __syncthreads();
  }
  if (threadIdx.x == 0) {
    if (blockIdx.x < 48) l1part[blockIdx.x] = red[0];
    else                 l0part[blockIdx.x - 48] = red[0];
  }
}

// ---------------- final: losses + mutual-NN precision/recall ----------------
__global__ void k_final(const int* __restrict__ c0, const int* __restrict__ c1,
                        const float* __restrict__ lg0, const float* __restrict__ lg1,
                        const unsigned* __restrict__ best0, const unsigned* __restrict__ best1,
                        const float* __restrict__ l0part, const float* __restrict__ l1part,
                        float* __restrict__ out) {
  const int tid = threadIdx.x;
  float l0s = 0.f, l1s = 0.f;
  int m0c = 0, m1c = 0, tpc = 0, prc = 0;
  if (tid < 48) { l0s = l0part[tid]; l1s = l1part[tid]; }
  for (int n = tid; n < NPTS; n += 256) {
    int cc = c0[n];
    bool m0 = cc >= 0;
    if (m0) m0c++;
    int b0 = (int)best0[n];
    bool mutual = ((int)best1[b0] == n);
    bool pred = mutual && (lg0[n] >= 0.f) && (lg1[b0] >= 0.f);
    if (pred) { prc++; if (m0 && b0 == cc) tpc++; }
    if (c1[n] >= 0) m1c++;
  }
  __shared__ float sf[256];
  __shared__ int si[256];
  sf[tid] = l0s; __syncthreads();
  for (int st = 128; st > 0; st >>= 1) { if (tid < st) sf[tid] += sf[tid + st]; __syncthreads(); }
  float L0 = sf[0]; __syncthreads();
  sf[tid] = l1s; __syncthreads();
  for (int st = 128; st > 0; st >>= 1) { if (tid < st) sf[tid] += sf[tid + st]; __syncthreads(); }
  float L1 = sf[0]; __syncthreads();
  si[tid] = m0c; __syncthreads();
  for (int st = 128; st > 0; st >>= 1) { if (tid < st) si[tid] += si[tid + st]; __syncthreads(); }
  int M0 = si[0]; __syncthreads();
  si[tid] = m1c; __syncthreads();
  for (int st = 128; st > 0; st >>= 1) { if (tid < st) si[tid] += si[tid + st]; __syncthreads(); }
  int M1 = si[0]; __syncthreads();
  si[tid] = tpc; __syncthreads();
  for (int st = 128; st > 0; st >>= 1) { if (tid < st) si[tid] += si[tid + st]; __syncthreads(); }
  int TP = si[0]; __syncthreads();
  si[tid] = prc; __syncthreads();
  for (int st = 128; st > 0; st >>= 1) { if (tid < st) si[tid] += si[tid + st]; __syncthreads(); }
  int PR = si[0];
  if (tid == 0) {
    out[0] = L0 / (float)(M0 > 0 ? M0 : 1);
    out[1] = L1 / (float)(M1 > 0 ? M1 : 1);
    out[2] = (float)TP / (float)(PR > 0 ? PR : 1);
    out[3] = (float)TP / (float)(M0 > 0 ? M0 : 1);
  }
}

extern "C" void kernel_launch(void* const* d_in, const int* in_sizes, int n_in,
                              void* d_out, int out_size, void* d_ws, size_t ws_size,
                              hipStream_t stream) {
  const float* desc0 = (const float*)d_in[0];
  const float* desc1 = (const float*)d_in[1];
  const int* corr0   = (const int*)d_in[2];
  const int* corr1   = (const int*)d_in[3];
  const float* lg0   = (const float*)d_in[4];
  const float* lg1   = (const float*)d_in[5];
  float* out = (float*)d_out;

  char* w = (char*)d_ws;
  short* d0b   = (short*)(w);                   // 3,145,728 B
  short* d1b   = (short*)(w + 3145728);         // 3,145,728 B
  uint2* colKV = (uint2*)(w + 6291456);         // 18,874,368 B  [192][12288]
  uint2* rowKV = (uint2*)(w + 25165824);        //  1,572,864 B  [16][12288]
  unsigned* best0 = (unsigned*)(w + 26738688);  //     49,152 B
  unsigned* best1 = (unsigned*)(w + 26787840);  //     49,152 B
  float* l0part = (float*)(w + 26836992);       //        192 B
  float* l1part = (float*)(w + 26837184);       //        192 B

  k_conv<<<3072, 256, 0, stream>>>(desc0, desc1, d0b, d1b);
  k_main<<<768, 256, 0, stream>>>(d0b, d1b, colKV, rowKV);
  k_red<<<96, 256, 0, stream>>>(colKV, rowKV, desc0, desc1, corr0, corr1, best0, best1, l0part, l1part);
  k_final<<<1, 256, 0, stream>>>(corr0, corr1, lg0, lg1, best0, best1, l0part, l1part, out);
}

// Round 5
// 203.548 us; speedup vs baseline: 1.1059x; 1.1059x over previous
//
#include <hip/hip_runtime.h>
#include <hip/hip_bf16.h>

#define NPTS 12288
#define DD 128
#define CHUNKS 16
#define CHW (NPTS / CHUNKS)   // 768 cols per chunk
#define TILES (CHW / 64)      // 12 col-tiles of 64
#define NBANDS (NPTS / 64)    // 192 row bands

// descriptors pre-scaled by sqrt(10 * log2(e)) so MFMA result a = S*log2(e);
// then e^S = exp2(a) directly and argmax keys come from bits(exp2(a)).
#define PRESCALE 3.79828262f

typedef short bf16x8 __attribute__((ext_vector_type(8)));
typedef float f32x4 __attribute__((ext_vector_type(4)));

__device__ __forceinline__ float fast_exp2(float x) {
#if defined(__has_builtin)
#if __has_builtin(__builtin_amdgcn_exp2f)
  return __builtin_amdgcn_exp2f(x);
#else
  return exp2f(x);
#endif
#else
  return exp2f(x);
#endif
}

__device__ __forceinline__ short f2bf(float f) {  // RNE f32 -> bf16
  unsigned u = __float_as_uint(f);
  u += 0x7FFFu + ((u >> 16) & 1u);
  return (short)(u >> 16);
}

__device__ __forceinline__ unsigned umax(unsigned a, unsigned b) { return a > b ? a : b; }

// ---------------- pure conversion: f32 -> prescaled bf16 ----------------
__global__ void k_conv(const float* __restrict__ d0, const float* __restrict__ d1,
                       short* __restrict__ o0, short* __restrict__ o1) {
  unsigned t = blockIdx.x * 256u + threadIdx.x;
  const unsigned half = (NPTS * DD) / 4;
  const float* src; short* dst; unsigned g;
  if (t < half) { src = d0; dst = o0; g = t; }
  else          { src = d1; dst = o1; g = t - half; }
  float4 v = *(const float4*)(src + (size_t)g * 4);
  short4 r;
  r.x = f2bf(v.x * PRESCALE); r.y = f2bf(v.y * PRESCALE);
  r.z = f2bf(v.z * PRESCALE); r.w = f2bf(v.w * PRESCALE);
  *(short4*)(dst + (size_t)g * 4) = r;
}

// ---------------- main fused kernel ----------------
// block = (band, chunk-group of 4). A band (64x128 bf16 = 16KB) staged once in
// LDS with XOR swizzle, shared by 4 waves; each wave owns one chunk.
// Software pipeline: per tile, MFMA (consumes breg) -> issue next tile's B
// loads -> epilogue (~1100 VALU cyc) covers the B load latency.
// C-frag: col = lane&15, row = (lane>>4)*4 + reg (m89/m91, verified R1-R4).
__launch_bounds__(256, 2)
__global__ void k_main(const short* __restrict__ d0b, const short* __restrict__ d1b,
                       uint2* __restrict__ colKV, uint2* __restrict__ rowKV) {
  __shared__ __align__(16) char aLds[64 * 256];   // 16 KB
  const int widx = threadIdx.x >> 6;
  const int lane = threadIdx.x & 63;
  const int lo = lane & 15, hi = lane >> 4;
  const int band = blockIdx.x >> 2;                // 0..191
  const int cg = blockIdx.x & 3;
  const int chunk = cg * 4 + widx;                 // 0..15
  const int row0 = band * 64;
  const int cbase = chunk * CHW;

  // stage A band into LDS, swizzled: lds[byte ^ ((row&7)<<4)] = global[byte]
  {
    const char* src = (const char*)(d0b + (size_t)row0 * DD);
    #pragma unroll
    for (int it = 0; it < 4; it++) {
      int byte = (it * 256 + threadIdx.x) * 16;    // 0..16383
      int row = byte >> 8;
      int swz = byte ^ ((row & 7) << 4);
      *(int4*)(aLds + swz) = *(const int4*)(src + byte);
    }
  }
  __syncthreads();

  float rowsum[4][4];
  unsigned rowkey[4][4];
  #pragma unroll
  for (int i = 0; i < 4; i++)
    #pragma unroll
    for (int r = 0; r < 4; r++) {
      rowsum[i][r] = 0.f;
      rowkey[i][r] = 0u;
    }
  // rowcomp recomputed inline from this single base (saves 16 regs)
  const unsigned rcbase = 0x3FFFu - (unsigned)(row0 + hi * 4);

  const short* bp0 = d1b + (size_t)cbase * DD;
  const int axor = (lo & 7) << 4;                  // lane-constant LDS swizzle term

  bf16x8 breg[4][4];                               // [kk][j], single buffer (64 VGPR)
  // prologue: load tile 0
  #pragma unroll
  for (int kk = 0; kk < 4; kk++)
    #pragma unroll
    for (int j = 0; j < 4; j++)
      breg[kk][j] = *(const bf16x8*)(bp0 + (size_t)(j * 16 + lo) * DD + kk * 32 + hi * 8);

  #pragma unroll 1
  for (int t = 0; t < TILES; t++) {
    // opaque zero: keeps A ds_reads inside the t-loop (prevents LICM hoist)
    int tblur = 0;
    asm volatile("" : "+v"(tblur));

    f32x4 acc[4][4];
    #pragma unroll
    for (int i = 0; i < 4; i++)
      #pragma unroll
      for (int j = 0; j < 4; j++)
        acc[i][j] = (f32x4){0.f, 0.f, 0.f, 0.f};

    // MFMA phase: A from LDS per kk, B from breg
    #pragma unroll
    for (int kk = 0; kk < 4; kk++) {
      bf16x8 afr[4];
      #pragma unroll
      for (int i = 0; i < 4; i++) {
        int abyte = (((i << 4) + lo) << 8) + (kk << 6) + (hi << 4);
        abyte ^= axor;
        afr[i] = *(const bf16x8*)(aLds + abyte + tblur);
      }
      #pragma unroll
      for (int j = 0; j < 4; j++)
        #pragma unroll
        for (int i = 0; i < 4; i++)
          acc[i][j] = __builtin_amdgcn_mfma_f32_16x16x32_bf16(afr[i], breg[kk][j], acc[i][j], 0, 0, 0);
    }

    __builtin_amdgcn_sched_barrier(0);

    // prefetch next tile's B into breg (WAR after MFMAs); epilogue hides latency
    if (t + 1 < TILES) {
      const short* bpt = bp0 + (size_t)(t + 1) * 64 * DD;
      #pragma unroll
      for (int kk = 0; kk < 4; kk++)
        #pragma unroll
        for (int j = 0; j < 4; j++)
          breg[kk][j] = *(const bf16x8*)(bpt + (size_t)(j * 16 + lo) * DD + kk * 32 + hi * 8);
    }

    // fused epilogue: e = e^S = exp2(a); keys from bits(e) (monotone), both directions
    const int ct = cbase + t * 64;
    #pragma unroll
    for (int j = 0; j < 4; j++) {
      float colsum = 0.f;
      unsigned colkey = 0u;
      const unsigned ccomp = 0x3FFFu - (unsigned)(ct + j * 16 + lo);
      #pragma unroll
      for (int i = 0; i < 4; i++)
        #pragma unroll
        for (int r = 0; r < 4; r++) {
          float e = fast_exp2(acc[i][j][r]);
          unsigned tb = __float_as_uint(e) & 0xFFFFC000u;
          rowkey[i][r] = umax(rowkey[i][r], tb | ccomp);
          colkey = umax(colkey, tb | (rcbase - (unsigned)(i * 16 + r)));
          rowsum[i][r] += e;
          colsum += e;
        }
      colsum += __shfl_xor(colsum, 16, 64);
      colsum += __shfl_xor(colsum, 32, 64);
      colkey = umax(colkey, (unsigned)__shfl_xor((int)colkey, 16, 64));
      colkey = umax(colkey, (unsigned)__shfl_xor((int)colkey, 32, 64));
      if (hi == 0) {
        int c = ct + j * 16 + lo;
        colKV[(size_t)band * NPTS + c] = make_uint2(colkey, __float_as_uint(colsum));
      }
    }
  }

  // row partials: reduce over lo bits (cols), lanes with lo==0 write
  #pragma unroll
  for (int i = 0; i < 4; i++)
    #pragma unroll
    for (int r = 0; r < 4; r++) {
      float s = rowsum[i][r];
      unsigned k = rowkey[i][r];
      s += __shfl_xor(s, 1, 64); s += __shfl_xor(s, 2, 64);
      s += __shfl_xor(s, 4, 64); s += __shfl_xor(s, 8, 64);
      k = umax(k, (unsigned)__shfl_xor((int)k, 1, 64));
      k = umax(k, (unsigned)__shfl_xor((int)k, 2, 64));
      k = umax(k, (unsigned)__shfl_xor((int)k, 4, 64));
      k = umax(k, (unsigned)__shfl_xor((int)k, 8, 64));
      if (lo == 0) {
        int row = row0 + i * 16 + hi * 4 + r;
        rowKV[(size_t)chunk * NPTS + row] = make_uint2(k, __float_as_uint(s));
      }
    }
}

// ---------------- fused reduce (+ exact positive dots): blocks 0..47 cols, 48..95 rows ----
__global__ void k_red(const uint2* __restrict__ colKV, const uint2* __restrict__ rowKV,
                      const float* __restrict__ d0, const float* __restrict__ d1,
                      const int* __restrict__ c0, const int* __restrict__ c1,
                      unsigned* __restrict__ best0, unsigned* __restrict__ best1,
                      float* __restrict__ l0part, float* __restrict__ l1part) {
  float v;
  if (blockIdx.x < 48) {
    int m = blockIdx.x * 256 + threadIdx.x;
    float s = 0.f; unsigned k = 0u;
    #pragma unroll 8
    for (int b = 0; b < NBANDS; b++) {
      uint2 kv = colKV[(size_t)b * NPTS + m];
      s += __uint_as_float(kv.y);
      k = umax(k, kv.x);
    }
    best1[m] = 0x3FFFu - (k & 0x3FFFu);
    int cc = c1[m];
    int i = cc > 0 ? cc : 0;
    const float4* pa = (const float4*)(d0 + (size_t)i * DD);
    const float4* pb = (const float4*)(d1 + (size_t)m * DD);
    float dot = 0.f;
    #pragma unroll 8
    for (int q = 0; q < DD / 4; q++) {
      float4 a = pa[q], b = pb[q];
      dot += a.x * b.x + a.y * b.y + a.z * b.z + a.w * b.w;
    }
    v = (cc >= 0) ? (logf(s) - 10.0f * dot) : 0.f;
  } else {
    int n = (blockIdx.x - 48) * 256 + threadIdx.x;
    float s = 0.f; unsigned k = 0u;
    #pragma unroll
    for (int c = 0; c < CHUNKS; c++) {
      uint2 kv = rowKV[(size_t)c * NPTS + n];
      s += __uint_as_float(kv.y);
      k = umax(k, kv.x);
    }
    best0[n] = 0x3FFFu - (k & 0x3FFFu);
    int cc = c0[n];
    int i = cc > 0 ? cc : 0;
    const float4* pa = (const float4*)(d0 + (size_t)n * DD);
    const float4* pb = (const float4*)(d1 + (size_t)i * DD);
    float dot = 0.f;
    #pragma unroll 8
    for (int q = 0; q < DD / 4; q++) {
      float4 a = pa[q], b = pb[q];
      dot += a.x * b.x + a.y * b.y + a.z * b.z + a.w * b.w;
    }
    v = (cc >= 0) ? (logf(s) - 10.0f * dot) : 0.f;
  }
  __shared__ float red[256];
  red[threadIdx.x] = v; __syncthreads();
  for (int st = 128; st > 0; st >>= 1) {
    if (threadIdx.x < st) red[threadIdx.x] += red[threadIdx.x + st];
    __syncthreads();
  }
  if (threadIdx.x == 0) {
    if (blockIdx.x < 48) l1part[blockIdx.x] = red[0];
    else                 l0part[blockIdx.x - 48] = red[0];
  }
}

// ---------------- final: losses + mutual-NN precision/recall ----------------
__global__ void k_final(const int* __restrict__ c0, const int* __restrict__ c1,
                        const float* __restrict__ lg0, const float* __restrict__ lg1,
                        const unsigned* __restrict__ best0, const unsigned* __restrict__ best1,
                        const float* __restrict__ l0part, const float* __restrict__ l1part,
                        float* __restrict__ out) {
  const int tid = threadIdx.x;
  float l0s = 0.f, l1s = 0.f;
  int m0c = 0, m1c = 0, tpc = 0, prc = 0;
  if (tid < 48) { l0s = l0part[tid]; l1s = l1part[tid]; }
  for (int n = tid; n < NPTS; n += 256) {
    int cc = c0[n];
    bool m0 = cc >= 0;
    if (m0) m0c++;
    int b0 = (int)best0[n];
    bool mutual = ((int)best1[b0] == n);
    bool pred = mutual && (lg0[n] >= 0.f) && (lg1[b0] >= 0.f);
    if (pred) { prc++; if (m0 && b0 == cc) tpc++; }
    if (c1[n] >= 0) m1c++;
  }
  __shared__ float sf[256];
  __shared__ int si[256];
  sf[tid] = l0s; __syncthreads();
  for (int st = 128; st > 0; st >>= 1) { if (tid < st) sf[tid] += sf[tid + st]; __syncthreads(); }
  float L0 = sf[0]; __syncthreads();
  sf[tid] = l1s; __syncthreads();
  for (int st = 128; st > 0; st >>= 1) { if (tid < st) sf[tid] += sf[tid + st]; __syncthreads(); }
  float L1 = sf[0]; __syncthreads();
  si[tid] = m0c; __syncthreads();
  for (int st = 128; st > 0; st >>= 1) { if (tid < st) si[tid] += si[tid + st]; __syncthreads(); }
  int M0 = si[0]; __syncthreads();
  si[tid] = m1c; __syncthreads();
  for (int st = 128; st > 0; st >>= 1) { if (tid < st) si[tid] += si[tid + st]; __syncthreads(); }
  int M1 = si[0]; __syncthreads();
  si[tid] = tpc; __syncthreads();
  for (int st = 128; st > 0; st >>= 1) { if (tid < st) si[tid] += si[tid + st]; __syncthreads(); }
  int TP = si[0]; __syncthreads();
  si[tid] = prc; __syncthreads();
  for (int st = 128; st > 0; st >>= 1) { if (tid < st) si[tid] += si[tid + st]; __syncthreads(); }
  int PR = si[0];
  if (tid == 0) {
    out[0] = L0 / (float)(M0 > 0 ? M0 : 1);
    out[1] = L1 / (float)(M1 > 0 ? M1 : 1);
    out[2] = (float)TP / (float)(PR > 0 ? PR : 1);
    out[3] = (float)TP / (float)(M0 > 0 ? M0 : 1);
  }
}

extern "C" void kernel_launch(void* const* d_in, const int* in_sizes, int n_in,
                              void* d_out, int out_size, void* d_ws, size_t ws_size,
                              hipStream_t stream) {
  const float* desc0 = (const float*)d_in[0];
  const float* desc1 = (const float*)d_in[1];
  const int* corr0   = (const int*)d_in[2];
  const int* corr1   = (const int*)d_in[3];
  const float* lg0   = (const float*)d_in[4];
  const float* lg1   = (const float*)d_in[5];
  float* out = (float*)d_out;

  char* w = (char*)d_ws;
  short* d0b   = (short*)(w);                   // 3,145,728 B
  short* d1b   = (short*)(w + 3145728);         // 3,145,728 B
  uint2* colKV = (uint2*)(w + 6291456);         // 18,874,368 B  [192][12288]
  uint2* rowKV = (uint2*)(w + 25165824);        //  1,572,864 B  [16][12288]
  unsigned* best0 = (unsigned*)(w + 26738688);  //     49,152 B
  unsigned* best1 = (unsigned*)(w + 26787840);  //     49,152 B
  float* l0part = (float*)(w + 26836992);       //        192 B
  float* l1part = (float*)(w + 26837184);       //        192 B

  k_conv<<<3072, 256, 0, stream>>>(desc0, desc1, d0b, d1b);
  k_main<<<768, 256, 0, stream>>>(d0b, d1b, colKV, rowKV);
  k_red<<<96, 256, 0, stream>>>(colKV, rowKV, desc0, desc1, corr0, corr1, best0, best1, l0part, l1part);
  k_final<<<1, 256, 0, stream>>>(corr0, corr1, lg0, lg1, best0, best1, l0part, l1part, out);
}

// Round 6
// 186.819 us; speedup vs baseline: 1.2049x; 1.0895x over previous
//
#include <hip/hip_runtime.h>
#include <hip/hip_bf16.h>

#define NPTS 12288
#define DD 128
#define CHUNKS 16
#define CHW (NPTS / CHUNKS)   // 768 cols per chunk
#define TILES (CHW / 64)      // 12 col-tiles of 64
#define NBANDS (NPTS / 64)    // 192 row bands

// descriptors pre-scaled by sqrt(10 * log2(e)) so MFMA result a = S*log2(e);
// then e^S = exp2(a) directly and argmax keys come from bits(exp2(a)).
#define PRESCALE 3.79828262f

typedef short bf16x8 __attribute__((ext_vector_type(8)));
typedef float f32x4 __attribute__((ext_vector_type(4)));

__device__ __forceinline__ float fast_exp2(float x) {
#if defined(__has_builtin)
#if __has_builtin(__builtin_amdgcn_exp2f)
  return __builtin_amdgcn_exp2f(x);
#else
  return exp2f(x);
#endif
#else
  return exp2f(x);
#endif
}

__device__ __forceinline__ short f2bf(float f) {  // RNE f32 -> bf16
  unsigned u = __float_as_uint(f);
  u += 0x7FFFu + ((u >> 16) & 1u);
  return (short)(u >> 16);
}

__device__ __forceinline__ unsigned umax(unsigned a, unsigned b) { return a > b ? a : b; }

// ---------------- pure conversion: f32 -> prescaled bf16 ----------------
__global__ void k_conv(const float* __restrict__ d0, const float* __restrict__ d1,
                       short* __restrict__ o0, short* __restrict__ o1) {
  unsigned t = blockIdx.x * 256u + threadIdx.x;
  const unsigned half = (NPTS * DD) / 4;
  const float* src; short* dst; unsigned g;
  if (t < half) { src = d0; dst = o0; g = t; }
  else          { src = d1; dst = o1; g = t - half; }
  float4 v = *(const float4*)(src + (size_t)g * 4);
  short4 r;
  r.x = f2bf(v.x * PRESCALE); r.y = f2bf(v.y * PRESCALE);
  r.z = f2bf(v.z * PRESCALE); r.w = f2bf(v.w * PRESCALE);
  *(short4*)(dst + (size_t)g * 4) = r;
}

// ---------------- main fused kernel ----------------
// block = (bandgroup of 4, chunk): 4 waves, wave w owns band bg*4+w; all waves
// share the chunk's B tiles, staged global->LDS async (double buffer, 2x16KB).
// LDS dest is linear (global_load_lds constraint); global SOURCE is
// pre-swizzled with the involution byte ^= ((byte>>8)&7)<<4, and ds_reads
// apply the same swizzle -> bank-balanced b128 reads (rule 21).
// A (64x128 bf16) hoisted in regs per wave (R3-proven: 128 VGPR, no spill).
// Per tile: stage(t+1) -> ds_read+MFMA(buf cur) -> fused epilogue (covers
// the in-flight loads) -> __syncthreads (vmcnt drain free by then).
// C-frag: col = lane&15, row = (lane>>4)*4 + reg (m89/m91, verified R1-R5).
__launch_bounds__(256, 2)
__global__ void k_main(const short* __restrict__ d0b, const short* __restrict__ d1b,
                       uint2* __restrict__ colKV, uint2* __restrict__ rowKV) {
  __shared__ __align__(16) char bLds[2][16384];
  const int widx = threadIdx.x >> 6;
  const int lane = threadIdx.x & 63;
  const int lo = lane & 15, hi = lane >> 4;
  const int chunk = blockIdx.x & (CHUNKS - 1);
  const int band = (blockIdx.x >> 4) * 4 + widx;   // 0..191
  const int row0 = band * 64;
  const int cbase = chunk * CHW;

  const char* btile0 = (const char*)(d1b + (size_t)cbase * DD);  // tile t at +t*16384

  // stage helper: wave w writes LDS [w*4096, w*4096+4096) linearly in 4 rounds;
  // global source pre-swizzled so that lds[linear] ends up = tile[linear^swz].
  #define STAGE(tt, bb) do {                                                   \
    const char* gsrc_ = btile0 + (size_t)(tt) * 16384;                         \
    _Pragma("unroll")                                                          \
    for (int it_ = 0; it_ < 4; it_++) {                                        \
      int L_ = (widx << 12) + (it_ << 10) + (lane << 4);                       \
      int so_ = L_ ^ (((L_ >> 8) & 7) << 4);                                   \
      __builtin_amdgcn_global_load_lds((const void*)(gsrc_ + so_),             \
          (void*)(&bLds[bb][(widx << 12) + (it_ << 10)]), 16, 0, 0);           \
    }                                                                          \
  } while (0)

  // A fragments for this wave's 64 rows, all of K=128 (held for whole kernel)
  bf16x8 af[4][4];
  #pragma unroll
  for (int i = 0; i < 4; i++)
    #pragma unroll
    for (int kk = 0; kk < 4; kk++)
      af[i][kk] = *(const bf16x8*)(d0b + (size_t)(row0 + i * 16 + lo) * DD + kk * 32 + hi * 8);

  float rowsum[4][4];
  unsigned rowkey[4][4];
  #pragma unroll
  for (int i = 0; i < 4; i++)
    #pragma unroll
    for (int r = 0; r < 4; r++) {
      rowsum[i][r] = 0.f;
      rowkey[i][r] = 0u;
    }
  const unsigned rcbase = 0x3FFFu - (unsigned)(row0 + hi * 4);
  const int axor = (lo & 7) << 4;                  // lane-constant read swizzle

  STAGE(0, 0);
  __syncthreads();   // implicit vmcnt(0) drain: tile 0 resident

  #pragma unroll 1
  for (int t = 0; t < TILES; t++) {
    const int cur = t & 1;
    if (t + 1 < TILES) STAGE(t + 1, cur ^ 1);

    f32x4 acc[4][4];
    #pragma unroll
    for (int i = 0; i < 4; i++)
      #pragma unroll
      for (int j = 0; j < 4; j++)
        acc[i][j] = (f32x4){0.f, 0.f, 0.f, 0.f};

    const char* bbuf = &bLds[cur][0];
    #pragma unroll
    for (int kk = 0; kk < 4; kk++) {
      bf16x8 bfr[4];
      #pragma unroll
      for (int j = 0; j < 4; j++) {
        int bbyte = (((j << 4) + lo) << 8) + (kk << 6) + (hi << 4);
        bbyte ^= axor;
        bfr[j] = *(const bf16x8*)(bbuf + bbyte);
      }
      #pragma unroll
      for (int j = 0; j < 4; j++)
        #pragma unroll
        for (int i = 0; i < 4; i++)
          acc[i][j] = __builtin_amdgcn_mfma_f32_16x16x32_bf16(af[i][kk], bfr[j], acc[i][j], 0, 0, 0);
    }

    // fused epilogue: e = e^S = exp2(a); keys from bits(e) (monotone), both directions
    const int ct = cbase + t * 64;
    #pragma unroll
    for (int j = 0; j < 4; j++) {
      float colsum = 0.f;
      unsigned colkey = 0u;
      const unsigned ccomp = 0x3FFFu - (unsigned)(ct + j * 16 + lo);
      #pragma unroll
      for (int i = 0; i < 4; i++)
        #pragma unroll
        for (int r = 0; r < 4; r++) {
          float e = fast_exp2(acc[i][j][r]);
          unsigned tb = __float_as_uint(e) & 0xFFFFC000u;
          rowkey[i][r] = umax(rowkey[i][r], tb | ccomp);
          colkey = umax(colkey, tb | (rcbase - (unsigned)(i * 16 + r)));
          rowsum[i][r] += e;
          colsum += e;
        }
      colsum += __shfl_xor(colsum, 16, 64);
      colsum += __shfl_xor(colsum, 32, 64);
      colkey = umax(colkey, (unsigned)__shfl_xor((int)colkey, 16, 64));
      colkey = umax(colkey, (unsigned)__shfl_xor((int)colkey, 32, 64));
      if (hi == 0) {
        int c = ct + j * 16 + lo;
        colKV[(size_t)band * NPTS + c] = make_uint2(colkey, __float_as_uint(colsum));
      }
    }

    __syncthreads();   // all waves done with buf[cur]; stage(t+1) drained (free)
  }

  // row partials: reduce over lo bits (cols), lanes with lo==0 write
  #pragma unroll
  for (int i = 0; i < 4; i++)
    #pragma unroll
    for (int r = 0; r < 4; r++) {
      float s = rowsum[i][r];
      unsigned k = rowkey[i][r];
      s += __shfl_xor(s, 1, 64); s += __shfl_xor(s, 2, 64);
      s += __shfl_xor(s, 4, 64); s += __shfl_xor(s, 8, 64);
      k = umax(k, (unsigned)__shfl_xor((int)k, 1, 64));
      k = umax(k, (unsigned)__shfl_xor((int)k, 2, 64));
      k = umax(k, (unsigned)__shfl_xor((int)k, 4, 64));
      k = umax(k, (unsigned)__shfl_xor((int)k, 8, 64));
      if (lo == 0) {
        int row = row0 + i * 16 + hi * 4 + r;
        rowKV[(size_t)chunk * NPTS + row] = make_uint2(k, __float_as_uint(s));
      }
    }
  #undef STAGE
}

// ---------------- fused reduce (+ exact positive dots): blocks 0..47 cols, 48..95 rows ----
__global__ void k_red(const uint2* __restrict__ colKV, const uint2* __restrict__ rowKV,
                      const float* __restrict__ d0, const float* __restrict__ d1,
                      const int* __restrict__ c0, const int* __restrict__ c1,
                      unsigned* __restrict__ best0, unsigned* __restrict__ best1,
                      float* __restrict__ l0part, float* __restrict__ l1part) {
  float v;
  if (blockIdx.x < 48) {
    int m = blockIdx.x * 256 + threadIdx.x;
    float s = 0.f; unsigned k = 0u;
    #pragma unroll 8
    for (int b = 0; b < NBANDS; b++) {
      uint2 kv = colKV[(size_t)b * NPTS + m];
      s += __uint_as_float(kv.y);
      k = umax(k, kv.x);
    }
    best1[m] = 0x3FFFu - (k & 0x3FFFu);
    int cc = c1[m];
    int i = cc > 0 ? cc : 0;
    const float4* pa = (const float4*)(d0 + (size_t)i * DD);
    const float4* pb = (const float4*)(d1 + (size_t)m * DD);
    float dot = 0.f;
    #pragma unroll 8
    for (int q = 0; q < DD / 4; q++) {
      float4 a = pa[q], b = pb[q];
      dot += a.x * b.x + a.y * b.y + a.z * b.z + a.w * b.w;
    }
    v = (cc >= 0) ? (logf(s) - 10.0f * dot) : 0.f;
  } else {
    int n = (blockIdx.x - 48) * 256 + threadIdx.x;
    float s = 0.f; unsigned k = 0u;
    #pragma unroll
    for (int c = 0; c < CHUNKS; c++) {
      uint2 kv = rowKV[(size_t)c * NPTS + n];
      s += __uint_as_float(kv.y);
      k = umax(k, kv.x);
    }
    best0[n] = 0x3FFFu - (k & 0x3FFFu);
    int cc = c0[n];
    int i = cc > 0 ? cc : 0;
    const float4* pa = (const float4*)(d0 + (size_t)n * DD);
    const float4* pb = (const float4*)(d1 + (size_t)i * DD);
    float dot = 0.f;
    #pragma unroll 8
    for (int q = 0; q < DD / 4; q++) {
      float4 a = pa[q], b = pb[q];
      dot += a.x * b.x + a.y * b.y + a.z * b.z + a.w * b.w;
    }
    v = (cc >= 0) ? (logf(s) - 10.0f * dot) : 0.f;
  }
  __shared__ float red[256];
  red[threadIdx.x] = v; __syncthreads();
  for (int st = 128; st > 0; st >>= 1) {
    if (threadIdx.x < st) red[threadIdx.x] += red[threadIdx.x + st];
    __syncthreads();
  }
  if (threadIdx.x == 0) {
    if (blockIdx.x < 48) l1part[blockIdx.x] = red[0];
    else                 l0part[blockIdx.x - 48] = red[0];
  }
}

// ---------------- final: losses + mutual-NN precision/recall ----------------
__global__ void k_final(const int* __restrict__ c0, const int* __restrict__ c1,
                        const float* __restrict__ lg0, const float* __restrict__ lg1,
                        const unsigned* __restrict__ best0, const unsigned* __restrict__ best1,
                        const float* __restrict__ l0part, const float* __restrict__ l1part,
                        float* __restrict__ out) {
  const int tid = threadIdx.x;
  float l0s = 0.f, l1s = 0.f;
  int m0c = 0, m1c = 0, tpc = 0, prc = 0;
  if (tid < 48) { l0s = l0part[tid]; l1s = l1part[tid]; }
  for (int n = tid; n < NPTS; n += 256) {
    int cc = c0[n];
    bool m0 = cc >= 0;
    if (m0) m0c++;
    int b0 = (int)best0[n];
    bool mutual = ((int)best1[b0] == n);
    bool pred = mutual && (lg0[n] >= 0.f) && (lg1[b0] >= 0.f);
    if (pred) { prc++; if (m0 && b0 == cc) tpc++; }
    if (c1[n] >= 0) m1c++;
  }
  __shared__ float sf[256];
  __shared__ int si[256];
  sf[tid] = l0s; __syncthreads();
  for (int st = 128; st > 0; st >>= 1) { if (tid < st) sf[tid] += sf[tid + st]; __syncthreads(); }
  float L0 = sf[0]; __syncthreads();
  sf[tid] = l1s; __syncthreads();
  for (int st = 128; st > 0; st >>= 1) { if (tid < st) sf[tid] += sf[tid + st]; __syncthreads(); }
  float L1 = sf[0]; __syncthreads();
  si[tid] = m0c; __syncthreads();
  for (int st = 128; st > 0; st >>= 1) { if (tid < st) si[tid] += si[tid + st]; __syncthreads(); }
  int M0 = si[0]; __syncthreads();
  si[tid] = m1c; __syncthreads();
  for (int st = 128; st > 0; st >>= 1) { if (tid < st) si[tid] += si[tid + st]; __syncthreads(); }
  int M1 = si[0]; __syncthreads();
  si[tid] = tpc; __syncthreads();
  for (int st = 128; st > 0; st >>= 1) { if (tid < st) si[tid] += si[tid + st]; __syncthreads(); }
  int TP = si[0]; __syncthreads();
  si[tid] = prc; __syncthreads();
  for (int st = 128; st > 0; st >>= 1) { if (tid < st) si[tid] += si[tid + st]; __syncthreads(); }
  int PR = si[0];
  if (tid == 0) {
    out[0] = L0 / (float)(M0 > 0 ? M0 : 1);
    out[1] = L1 / (float)(M1 > 0 ? M1 : 1);
    out[2] = (float)TP / (float)(PR > 0 ? PR : 1);
    out[3] = (float)TP / (float)(M0 > 0 ? M0 : 1);
  }
}

extern "C" void kernel_launch(void* const* d_in, const int* in_sizes, int n_in,
                              void* d_out, int out_size, void* d_ws, size_t ws_size,
                              hipStream_t stream) {
  const float* desc0 = (const float*)d_in[0];
  const float* desc1 = (const float*)d_in[1];
  const int* corr0   = (const int*)d_in[2];
  const int* corr1   = (const int*)d_in[3];
  const float* lg0   = (const float*)d_in[4];
  const float* lg1   = (const float*)d_in[5];
  float* out = (float*)d_out;

  char* w = (char*)d_ws;
  short* d0b   = (short*)(w);                   // 3,145,728 B
  short* d1b   = (short*)(w + 3145728);         // 3,145,728 B
  uint2* colKV = (uint2*)(w + 6291456);         // 18,874,368 B  [192][12288]
  uint2* rowKV = (uint2*)(w + 25165824);        //  1,572,864 B  [16][12288]
  unsigned* best0 = (unsigned*)(w + 26738688);  //     49,152 B
  unsigned* best1 = (unsigned*)(w + 26787840);  //     49,152 B
  float* l0part = (float*)(w + 26836992);       //        192 B
  float* l1part = (float*)(w + 26837184);       //        192 B

  k_conv<<<3072, 256, 0, stream>>>(desc0, desc1, d0b, d1b);
  k_main<<<768, 256, 0, stream>>>(d0b, d1b, colKV, rowKV);
  k_red<<<96, 256, 0, stream>>>(colKV, rowKV, desc0, desc1, corr0, corr1, best0, best1, l0part, l1part);
  k_final<<<1, 256, 0, stream>>>(corr0, corr1, lg0, lg1, best0, best1, l0part, l1part, out);
}

// Round 7
// 155.660 us; speedup vs baseline: 1.4461x; 1.2002x over previous
//
#include <hip/hip_runtime.h>
#include <hip/hip_bf16.h>

#define NPTS 12288
#define DD 128
#define CHUNKS 16
#define CHW (NPTS / CHUNKS)   // 768 cols per chunk
#define TILES (CHW / 64)      // 12 col-tiles of 64
#define NBG (NPTS / 128)      // 96 col-partial groups (128 rows each)

// descriptors pre-scaled by sqrt(10 * log2(e)) so MFMA result a = S*log2(e);
// then e^S = exp2(a) directly and argmax keys come from bits(exp2(a)).
#define PRESCALE 3.79828262f

typedef short bf16x8 __attribute__((ext_vector_type(8)));
typedef float f32x4 __attribute__((ext_vector_type(4)));

__device__ __forceinline__ float fast_exp2(float x) {
#if defined(__has_builtin)
#if __has_builtin(__builtin_amdgcn_exp2f)
  return __builtin_amdgcn_exp2f(x);
#else
  return exp2f(x);
#endif
#else
  return exp2f(x);
#endif
}

__device__ __forceinline__ short f2bf(float f) {  // RNE f32 -> bf16
  unsigned u = __float_as_uint(f);
  u += 0x7FFFu + ((u >> 16) & 1u);
  return (short)(u >> 16);
}

__device__ __forceinline__ unsigned umax(unsigned a, unsigned b) { return a > b ? a : b; }

// ---------------- pure conversion: f32 -> prescaled bf16 ----------------
__global__ void k_conv(const float* __restrict__ d0, const float* __restrict__ d1,
                       short* __restrict__ o0, short* __restrict__ o1) {
  unsigned t = blockIdx.x * 256u + threadIdx.x;
  const unsigned half = (NPTS * DD) / 4;
  const float* src; short* dst; unsigned g;
  if (t < half) { src = d0; dst = o0; g = t; }
  else          { src = d1; dst = o1; g = t - half; }
  float4 v = *(const float4*)(src + (size_t)g * 4);
  short4 r;
  r.x = f2bf(v.x * PRESCALE); r.y = f2bf(v.y * PRESCALE);
  r.z = f2bf(v.z * PRESCALE); r.w = f2bf(v.w * PRESCALE);
  *(short4*)(dst + (size_t)g * 4) = r;
}

// ---------------- main fused kernel ----------------
// block = (bandgroup of 128 rows, chunk): 4 waves, wave w owns rows
// bg*128 + w*32 .. +31 (32x64 wave tile -> acc only 32 AGPR, af 32 VGPR,
// ~130 total regs -> 3 waves/SIMD with __launch_bounds__(256,3)).
// B staged global->LDS async (double buffer 2x16KB, R6 scheme: linear LDS
// dest, pre-swizzled global source, swizzled ds_read - rule 21).
// Col partials combined across the block's 4 waves in LDS per tile
// (crLds double-buffered by t&1), wave 0 stores one uint2 per column.
// Argmax keys are positive floats (bits(exp2(a)) masked | index-complement);
// float max == uint max for positives -> nested fmaxf fuses to v_max3_f32.
// C-frag: col = lane&15, row = (lane>>4)*4 + reg (m89/m91, verified R1-R6).
__launch_bounds__(256, 3)
__global__ void k_main(const short* __restrict__ d0b, const short* __restrict__ d1b,
                       uint2* __restrict__ colKV, uint2* __restrict__ rowKV) {
  __shared__ __align__(16) char bLds[2][16384];
  __shared__ uint2 crLds[2][4][64];
  const int widx = threadIdx.x >> 6;
  const int lane = threadIdx.x & 63;
  const int lo = lane & 15, hi = lane >> 4;
  const int chunk = blockIdx.x & (CHUNKS - 1);
  const int bg = blockIdx.x >> 4;                  // 0..95
  const int row0 = bg * 128 + widx * 32;
  const int cbase = chunk * CHW;

  const char* btile0 = (const char*)(d1b + (size_t)cbase * DD);  // tile t at +t*16384

  // stage helper: wave w writes LDS [w*4096, +4096) linearly in 4 rounds;
  // global source pre-swizzled so lds[linear] = tile[linear^swz].
  #define STAGE(tt, bb) do {                                                   \
    const char* gsrc_ = btile0 + (size_t)(tt) * 16384;                         \
    _Pragma("unroll")                                                          \
    for (int it_ = 0; it_ < 4; it_++) {                                        \
      int L_ = (widx << 12) + (it_ << 10) + (lane << 4);                       \
      int so_ = L_ ^ (((L_ >> 8) & 7) << 4);                                   \
      __builtin_amdgcn_global_load_lds((const void*)(gsrc_ + so_),             \
          (void*)(&bLds[bb][(widx << 12) + (it_ << 10)]), 16, 0, 0);           \
    }                                                                          \
  } while (0)

  // A fragments for this wave's 32 rows, all of K=128 (held whole kernel)
  bf16x8 af[2][4];
  #pragma unroll
  for (int i = 0; i < 2; i++)
    #pragma unroll
    for (int kk = 0; kk < 4; kk++)
      af[i][kk] = *(const bf16x8*)(d0b + (size_t)(row0 + i * 16 + lo) * DD + kk * 32 + hi * 8);

  float rowsum[2][4], rowkeyf[2][4];
  #pragma unroll
  for (int i = 0; i < 2; i++)
    #pragma unroll
    for (int r = 0; r < 4; r++) {
      rowsum[i][r] = 0.f;
      rowkeyf[i][r] = 0.f;
    }
  const unsigned rcbase = 0x3FFFu - (unsigned)(row0 + hi * 4);
  const int axor = (lo & 7) << 4;                  // lane-constant read swizzle

  STAGE(0, 0);
  __syncthreads();   // vmcnt(0) drain: tile 0 resident

  #pragma unroll 1
  for (int t = 0; t < TILES; t++) {
    const int cur = t & 1;
    if (t + 1 < TILES) STAGE(t + 1, cur ^ 1);

    f32x4 acc[2][4];
    #pragma unroll
    for (int i = 0; i < 2; i++)
      #pragma unroll
      for (int j = 0; j < 4; j++)
        acc[i][j] = (f32x4){0.f, 0.f, 0.f, 0.f};

    const char* bbuf = &bLds[cur][0];
    #pragma unroll
    for (int kk = 0; kk < 4; kk++) {
      bf16x8 bfr[4];
      #pragma unroll
      for (int j = 0; j < 4; j++) {
        int bbyte = (((j << 4) + lo) << 8) + (kk << 6) + (hi << 4);
        bbyte ^= axor;
        bfr[j] = *(const bf16x8*)(bbuf + bbyte);
      }
      #pragma unroll
      for (int j = 0; j < 4; j++)
        #pragma unroll
        for (int i = 0; i < 2; i++)
          acc[i][j] = __builtin_amdgcn_mfma_f32_16x16x32_bf16(af[i][kk], bfr[j], acc[i][j], 0, 0, 0);
    }

    // fused epilogue: e = e^S = exp2(a); float-typed keys (max3-fusable)
    const int ct = cbase + t * 64;
    #pragma unroll
    for (int j = 0; j < 4; j++) {
      float colsum = 0.f;
      float colkeyf = 0.f;
      const unsigned ccomp = 0x3FFFu - (unsigned)(ct + j * 16 + lo);
      #pragma unroll
      for (int i = 0; i < 2; i++)
        #pragma unroll
        for (int r = 0; r < 4; r++) {
          float e = fast_exp2(acc[i][j][r]);
          unsigned tb = __float_as_uint(e) & 0xFFFFC000u;
          rowkeyf[i][r] = fmaxf(rowkeyf[i][r], __uint_as_float(tb | ccomp));
          colkeyf = fmaxf(colkeyf, __uint_as_float(tb | (rcbase - (unsigned)(i * 16 + r))));
          rowsum[i][r] += e;
          colsum += e;
        }
      colsum += __shfl_xor(colsum, 16, 64);
      colsum += __shfl_xor(colsum, 32, 64);
      colkeyf = fmaxf(colkeyf, __shfl_xor(colkeyf, 16, 64));
      colkeyf = fmaxf(colkeyf, __shfl_xor(colkeyf, 32, 64));
      if (hi == 0)
        crLds[cur][widx][j * 16 + lo] = make_uint2(__float_as_uint(colkeyf), __float_as_uint(colsum));
    }

    __syncthreads();   // crLds visible; bLds[cur^1] staged; all done with buf[cur]

    // wave 0: combine 4 waves' col partials, one store per column
    if (threadIdx.x < 64) {
      int c = threadIdx.x;
      uint2 p0 = crLds[cur][0][c], p1 = crLds[cur][1][c];
      uint2 p2 = crLds[cur][2][c], p3 = crLds[cur][3][c];
      float s = __uint_as_float(p0.y) + __uint_as_float(p1.y) +
                __uint_as_float(p2.y) + __uint_as_float(p3.y);
      float k = fmaxf(fmaxf(__uint_as_float(p0.x), __uint_as_float(p1.x)),
                      fmaxf(__uint_as_float(p2.x), __uint_as_float(p3.x)));
      colKV[(size_t)bg * NPTS + ct + c] = make_uint2(__float_as_uint(k), __float_as_uint(s));
    }
  }

  // row partials: reduce over lo bits (cols), lanes with lo==0 write
  #pragma unroll
  for (int i = 0; i < 2; i++)
    #pragma unroll
    for (int r = 0; r < 4; r++) {
      float s = rowsum[i][r];
      float k = rowkeyf[i][r];
      s += __shfl_xor(s, 1, 64); s += __shfl_xor(s, 2, 64);
      s += __shfl_xor(s, 4, 64); s += __shfl_xor(s, 8, 64);
      k = fmaxf(k, __shfl_xor(k, 1, 64));
      k = fmaxf(k, __shfl_xor(k, 2, 64));
      k = fmaxf(k, __shfl_xor(k, 4, 64));
      k = fmaxf(k, __shfl_xor(k, 8, 64));
      if (lo == 0) {
        int row = row0 + i * 16 + hi * 4 + r;
        rowKV[(size_t)chunk * NPTS + row] = make_uint2(__float_as_uint(k), __float_as_uint(s));
      }
    }
  #undef STAGE
}

// ---------------- fused reduce (+ exact positive dots): blocks 0..47 cols, 48..95 rows ----
__global__ void k_red(const uint2* __restrict__ colKV, const uint2* __restrict__ rowKV,
                      const float* __restrict__ d0, const float* __restrict__ d1,
                      const int* __restrict__ c0, const int* __restrict__ c1,
                      unsigned* __restrict__ best0, unsigned* __restrict__ best1,
                      float* __restrict__ l0part, float* __restrict__ l1part) {
  float v;
  if (blockIdx.x < 48) {
    int m = blockIdx.x * 256 + threadIdx.x;
    float s = 0.f; unsigned k = 0u;
    #pragma unroll 8
    for (int b = 0; b < NBG; b++) {
      uint2 kv = colKV[(size_t)b * NPTS + m];
      s += __uint_as_float(kv.y);
      k = umax(k, kv.x);
    }
    best1[m] = 0x3FFFu - (k & 0x3FFFu);
    int cc = c1[m];
    int i = cc > 0 ? cc : 0;
    const float4* pa = (const float4*)(d0 + (size_t)i * DD);
    const float4* pb = (const float4*)(d1 + (size_t)m * DD);
    float dot = 0.f;
    #pragma unroll 8
    for (int q = 0; q < DD / 4; q++) {
      float4 a = pa[q], b = pb[q];
      dot += a.x * b.x + a.y * b.y + a.z * b.z + a.w * b.w;
    }
    v = (cc >= 0) ? (logf(s) - 10.0f * dot) : 0.f;
  } else {
    int n = (blockIdx.x - 48) * 256 + threadIdx.x;
    float s = 0.f; unsigned k = 0u;
    #pragma unroll
    for (int c = 0; c < CHUNKS; c++) {
      uint2 kv = rowKV[(size_t)c * NPTS + n];
      s += __uint_as_float(kv.y);
      k = umax(k, kv.x);
    }
    best0[n] = 0x3FFFu - (k & 0x3FFFu);
    int cc = c0[n];
    int i = cc > 0 ? cc : 0;
    const float4* pa = (const float4*)(d0 + (size_t)n * DD);
    const float4* pb = (const float4*)(d1 + (size_t)i * DD);
    float dot = 0.f;
    #pragma unroll 8
    for (int q = 0; q < DD / 4; q++) {
      float4 a = pa[q], b = pb[q];
      dot += a.x * b.x + a.y * b.y + a.z * b.z + a.w * b.w;
    }
    v = (cc >= 0) ? (logf(s) - 10.0f * dot) : 0.f;
  }
  __shared__ float red[256];
  red[threadIdx.x] = v; __syncthreads();
  for (int st = 128; st > 0; st >>= 1) {
    if (threadIdx.x < st) red[threadIdx.x] += red[threadIdx.x + st];
    __syncthreads();
  }
  if (threadIdx.x == 0) {
    if (blockIdx.x < 48) l1part[blockIdx.x] = red[0];
    else                 l0part[blockIdx.x - 48] = red[0];
  }
}

// ---------------- final: losses + mutual-NN precision/recall ----------------
__global__ void k_final(const int* __restrict__ c0, const int* __restrict__ c1,
                        const float* __restrict__ lg0, const float* __restrict__ lg1,
                        const unsigned* __restrict__ best0, const unsigned* __restrict__ best1,
                        const float* __restrict__ l0part, const float* __restrict__ l1part,
                        float* __restrict__ out) {
  const int tid = threadIdx.x;
  float l0s = 0.f, l1s = 0.f;
  int m0c = 0, m1c = 0, tpc = 0, prc = 0;
  if (tid < 48) { l0s = l0part[tid]; l1s = l1part[tid]; }
  for (int n = tid; n < NPTS; n += 256) {
    int cc = c0[n];
    bool m0 = cc >= 0;
    if (m0) m0c++;
    int b0 = (int)best0[n];
    bool mutual = ((int)best1[b0] == n);
    bool pred = mutual && (lg0[n] >= 0.f) && (lg1[b0] >= 0.f);
    if (pred) { prc++; if (m0 && b0 == cc) tpc++; }
    if (c1[n] >= 0) m1c++;
  }
  __shared__ float sf[256];
  __shared__ int si[256];
  sf[tid] = l0s; __syncthreads();
  for (int st = 128; st > 0; st >>= 1) { if (tid < st) sf[tid] += sf[tid + st]; __syncthreads(); }
  float L0 = sf[0]; __syncthreads();
  sf[tid] = l1s; __syncthreads();
  for (int st = 128; st > 0; st >>= 1) { if (tid < st) sf[tid] += sf[tid + st]; __syncthreads(); }
  float L1 = sf[0]; __syncthreads();
  si[tid] = m0c; __syncthreads();
  for (int st = 128; st > 0; st >>= 1) { if (tid < st) si[tid] += si[tid + st]; __syncthreads(); }
  int M0 = si[0]; __syncthreads();
  si[tid] = m1c; __syncthreads();
  for (int st = 128; st > 0; st >>= 1) { if (tid < st) si[tid] += si[tid + st]; __syncthreads(); }
  int M1 = si[0]; __syncthreads();
  si[tid] = tpc; __syncthreads();
  for (int st = 128; st > 0; st >>= 1) { if (tid < st) si[tid] += si[tid + st]; __syncthreads(); }
  int TP = si[0]; __syncthreads();
  si[tid] = prc; __syncthreads();
  for (int st = 128; st > 0; st >>= 1) { if (tid < st) si[tid] += si[tid + st]; __syncthreads(); }
  int PR = si[0];
  if (tid == 0) {
    out[0] = L0 / (float)(M0 > 0 ? M0 : 1);
    out[1] = L1 / (float)(M1 > 0 ? M1 : 1);
    out[2] = (float)TP / (float)(PR > 0 ? PR : 1);
    out[3] = (float)TP / (float)(M0 > 0 ? M0 : 1);
  }
}

extern "C" void kernel_launch(void* const* d_in, const int* in_sizes, int n_in,
                              void* d_out, int out_size, void* d_ws, size_t ws_size,
                              hipStream_t stream) {
  const float* desc0 = (const float*)d_in[0];
  const float* desc1 = (const float*)d_in[1];
  const int* corr0   = (const int*)d_in[2];
  const int* corr1   = (const int*)d_in[3];
  const float* lg0   = (const float*)d_in[4];
  const float* lg1   = (const float*)d_in[5];
  float* out = (float*)d_out;

  char* w = (char*)d_ws;
  short* d0b   = (short*)(w);                   // 3,145,728 B
  short* d1b   = (short*)(w + 3145728);         // 3,145,728 B
  uint2* colKV = (uint2*)(w + 6291456);         //  9,437,184 B  [96][12288]
  uint2* rowKV = (uint2*)(w + 15728640);        //  1,572,864 B  [16][12288]
  unsigned* best0 = (unsigned*)(w + 17301504);  //     49,152 B
  unsigned* best1 = (unsigned*)(w + 17350656);  //     49,152 B
  float* l0part = (float*)(w + 17399808);       //        192 B
  float* l1part = (float*)(w + 17400000);       //        192 B

  k_conv<<<3072, 256, 0, stream>>>(desc0, desc1, d0b, d1b);
  k_main<<<1536, 256, 0, stream>>>(d0b, d1b, colKV, rowKV);
  k_red<<<96, 256, 0, stream>>>(colKV, rowKV, desc0, desc1, corr0, corr1, best0, best1, l0part, l1part);
  k_final<<<1, 256, 0, stream>>>(corr0, corr1, lg0, lg1, best0, best1, l0part, l1part, out);
}